// Round 7
// baseline (472.797 us; speedup 1.0000x reference)
//
#include <hip/hip_runtime.h>

typedef unsigned int u32;
typedef unsigned short u16;
typedef __attribute__((ext_vector_type(8))) short bf16x8;
typedef __attribute__((ext_vector_type(4))) float f32x4;

#define MARGIN 1e-3f
#define MFMA16(a,b,c) __builtin_amdgcn_mfma_f32_16x16x32_bf16(a, b, c, 0, 0, 0)

__device__ __forceinline__ u16 bf16rn(float f){
    u32 u = __float_as_uint(f);
    return (u16)((u + 0x7fffu + ((u >> 16) & 1u)) >> 16);
}
__device__ __forceinline__ float bfup(u16 h){ return __uint_as_float(((u32)h) << 16); }

// ---- pre-pass: LDS-tiled transpose+convert, coalesced reads, uint4-packed writes ----
__global__ __launch_bounds__(256) void conv_kernel(
    const float* __restrict__ Wt1, const float* __restrict__ Wp1,
    const float* __restrict__ Wt2, const float* __restrict__ Wp2,
    u16* __restrict__ wt1hi, u16* __restrict__ wt1lo, u16* __restrict__ wp1hi,
    float* __restrict__ wt2t, float* __restrict__ wp2t)
{
    __shared__ float tile[64][68];
    const int t = threadIdx.x;
    const int b = blockIdx.x;

    if (b == 112) {
        for (int i = t; i < 5120; i += 256) {
            int n = i / 10, c = i % 10;
            wt2t[c * 512 + n] = Wt2[i];
        }
        for (int i = t; i < 12800; i += 256) {
            int p = i / 1280, r = i % 1280, n = r / 10, c = r % 10;
            wp2t[p * 1280 + c * 128 + n] = Wp2[i];
        }
        return;
    }

    const float* src; int src_ld, kt, nt;
    u16 *dhi, *dlo;
    if (b < 32) {
        kt = b & 3; nt = b >> 2;
        src = Wt1 + (size_t)(kt * 64) * 512 + nt * 64; src_ld = 512;
        dhi = wt1hi + (size_t)(nt * 64) * 256 + kt * 64;
        dlo = wt1lo + (size_t)(nt * 64) * 256 + kt * 64;
    } else {
        int j = b - 32, p = j >> 3, r = j & 7;
        kt = r & 3; nt = r >> 2;
        src = Wp1 + (size_t)p * 32768 + (size_t)(kt * 64) * 128 + nt * 64; src_ld = 128;
        dhi = wp1hi + (size_t)p * 32768 + (size_t)(nt * 64) * 256 + kt * 64;
        dlo = nullptr;
    }
    {
        const int kr = t >> 2, c0 = (t & 3) * 16;
        #pragma unroll
        for (int u = 0; u < 4; ++u) {
            float4 v = *(const float4*)(src + (size_t)kr * src_ld + c0 + u * 4);
            tile[kr][c0 + u*4 + 0] = v.x;
            tile[kr][c0 + u*4 + 1] = v.y;
            tile[kr][c0 + u*4 + 2] = v.z;
            tile[kr][c0 + u*4 + 3] = v.w;
        }
    }
    __syncthreads();
    {
        const int nr = t >> 2, k0 = (t & 3) * 16;
        u32 hw[8], lw[8];
        #pragma unroll
        for (int j = 0; j < 8; ++j) {
            float f0 = tile[k0 + 2*j][nr], f1 = tile[k0 + 2*j + 1][nr];
            u16 h0 = bf16rn(f0), h1 = bf16rn(f1);
            u16 l0 = bf16rn(f0 - bfup(h0)), l1 = bf16rn(f1 - bfup(h1));
            hw[j] = (u32)h0 | ((u32)h1 << 16);
            lw[j] = (u32)l0 | ((u32)l1 << 16);
        }
        uint4* dh = (uint4*)(dhi + (size_t)nr * 256 + k0);   // 32B-aligned
        dh[0] = (uint4){hw[0], hw[1], hw[2], hw[3]};
        dh[1] = (uint4){hw[4], hw[5], hw[6], hw[7]};
        if (dlo) {
            uint4* dl = (uint4*)(dlo + (size_t)nr * 256 + k0);
            dl[0] = (uint4){lw[0], lw[1], lw[2], lw[3]};
            dl[1] = (uint4){lw[4], lw[5], lw[6], lw[7]};
        }
    }
}

__global__ __launch_bounds__(512, 2) void netsum_kernel(
    const float* __restrict__ x,   const float* __restrict__ Wt1, const float* __restrict__ bt1,
    const float* __restrict__ bt2,
    const float* __restrict__ bp1, const float* __restrict__ bp2,
    const int* __restrict__ rdd,
    const u16* __restrict__ wt1hi, const u16* __restrict__ wt1lo, const u16* __restrict__ wp1hi,
    const float* __restrict__ wt2t, const float* __restrict__ wp2t,
    float* __restrict__ out)
{
    __shared__ u16 xhi[64][264];    // 33.8 KB
    __shared__ u16 xlo[64][264];    // 33.8 KB
    __shared__ float lg[64][10];
    __shared__ float oacc[64][10];
    __shared__ u32 plist[10][64];
    __shared__ u32 pcnt[10];
    __shared__ int rdds[20];
    __shared__ u32 elist[64];
    __shared__ u32 ecnt;
    __shared__ u32 wq[80];
    __shared__ u32 nwork;
    // ~76 KB -> 2 blocks/CU

    const int t = threadIdx.x;
    const int lane = t & 63;
    const int w = t >> 6;          // 8 waves
    const int ln = lane & 15;
    const int quad = lane >> 4;
    const int row0 = blockIdx.x * 64;

    if (t < 10) pcnt[t] = 0;
    if (t < 20) rdds[t] = rdd[t];
    if (t == 0) { ecnt = 0; nwork = 0; }
    for (int i = t; i < 640; i += 512) {
        ((float*)lg)[i] = bt2[i % 10];
        ((float*)oacc)[i] = 0.f;
    }

    // ---- stage x -> bf16 hi/lo in LDS ----
    {
        #pragma unroll
        for (int i = 0; i < 8; ++i) {
            int f = t + 512 * i;
            int r = f >> 6, c4 = f & 63;
            float4 v = *(const float4*)(x + (size_t)(row0 + r) * 256 + c4 * 4);
            u16 h0 = bf16rn(v.x), h1 = bf16rn(v.y), h2 = bf16rn(v.z), h3 = bf16rn(v.w);
            u16 l0 = bf16rn(v.x - bfup(h0)), l1 = bf16rn(v.y - bfup(h1));
            u16 l2 = bf16rn(v.z - bfup(h2)), l3 = bf16rn(v.w - bfup(h3));
            uint2 hw = { (u32)h0 | ((u32)h1 << 16), (u32)h2 | ((u32)h3 << 16) };
            uint2 lw = { (u32)l0 | ((u32)l1 << 16), (u32)l2 | ((u32)l3 << 16) };
            *(uint2*)&xhi[r][c4 * 4] = hw;
            *(uint2*)&xlo[r][c4 * 4] = lw;
        }
    }
    __syncthreads();

    // ---- layer 1: waves partition n only (wave w: n-tiles w*4..w*4+3, all 64 rows) ----
    {
        #pragma unroll
        for (int g = 0; g < 2; ++g) {
            f32x4 acc[4][2];
            #pragma unroll
            for (int mt = 0; mt < 4; ++mt) {
                acc[mt][0] = (f32x4){0.f,0.f,0.f,0.f};
                acc[mt][1] = (f32x4){0.f,0.f,0.f,0.f};
            }
            const int n0 = (w * 4 + g * 2) * 16 + ln;
            const int n1 = n0 + 16;
            const u16* b0h = wt1hi + n0 * 256;
            const u16* b0l = wt1lo + n0 * 256;
            const u16* b1h = wt1hi + n1 * 256;
            const u16* b1l = wt1lo + n1 * 256;

            int ko = quad * 8;
            bf16x8 bh0 = *(const bf16x8*)(b0h + ko);
            bf16x8 bl0 = *(const bf16x8*)(b0l + ko);
            bf16x8 bh1 = *(const bf16x8*)(b1h + ko);
            bf16x8 bl1 = *(const bf16x8*)(b1l + ko);
            #pragma unroll
            for (int kk = 0; kk < 8; ++kk) {
                bf16x8 nbh0, nbl0, nbh1, nbl1;
                if (kk < 7) {                       // prefetch next k-slice
                    nbh0 = *(const bf16x8*)(b0h + ko + 32);
                    nbl0 = *(const bf16x8*)(b0l + ko + 32);
                    nbh1 = *(const bf16x8*)(b1h + ko + 32);
                    nbl1 = *(const bf16x8*)(b1l + ko + 32);
                }
                #pragma unroll
                for (int mt = 0; mt < 4; ++mt) {
                    bf16x8 ah = *(const bf16x8*)(&xhi[mt * 16 + ln][ko]);
                    bf16x8 al = *(const bf16x8*)(&xlo[mt * 16 + ln][ko]);
                    acc[mt][0] = MFMA16(ah, bh0, acc[mt][0]);
                    acc[mt][0] = MFMA16(ah, bl0, acc[mt][0]);
                    acc[mt][0] = MFMA16(al, bh0, acc[mt][0]);
                    acc[mt][1] = MFMA16(ah, bh1, acc[mt][1]);
                    acc[mt][1] = MFMA16(ah, bl1, acc[mt][1]);
                    acc[mt][1] = MFMA16(al, bh1, acc[mt][1]);
                }
                ko += 32;
                bh0 = nbh0; bl0 = nbl0; bh1 = nbh1; bl1 = nbl1;
            }

            // epilogue: relu + Wt2 partials; bias/wv hoisted across m-tiles
            const float bias0 = bt1[n0], bias1 = bt1[n1];
            float wv0[10], wv1[10];
            #pragma unroll
            for (int c = 0; c < 10; ++c) { wv0[c] = wt2t[c * 512 + n0]; wv1[c] = wt2t[c * 512 + n1]; }
            #pragma unroll
            for (int mt = 0; mt < 4; ++mt) {
                float lp[4][10];
                #pragma unroll
                for (int r2 = 0; r2 < 4; ++r2)
                    #pragma unroll
                    for (int c = 0; c < 10; ++c) lp[r2][c] = 0.f;
                {
                    float h0 = acc[mt][0].x + bias0; h0 = h0 > 0.f ? h0 : 0.f;
                    float h1 = acc[mt][0].y + bias0; h1 = h1 > 0.f ? h1 : 0.f;
                    float h2 = acc[mt][0].z + bias0; h2 = h2 > 0.f ? h2 : 0.f;
                    float h3 = acc[mt][0].w + bias0; h3 = h3 > 0.f ? h3 : 0.f;
                    #pragma unroll
                    for (int c = 0; c < 10; ++c) {
                        lp[0][c] += h0 * wv0[c]; lp[1][c] += h1 * wv0[c];
                        lp[2][c] += h2 * wv0[c]; lp[3][c] += h3 * wv0[c];
                    }
                }
                {
                    float h0 = acc[mt][1].x + bias1; h0 = h0 > 0.f ? h0 : 0.f;
                    float h1 = acc[mt][1].y + bias1; h1 = h1 > 0.f ? h1 : 0.f;
                    float h2 = acc[mt][1].z + bias1; h2 = h2 > 0.f ? h2 : 0.f;
                    float h3 = acc[mt][1].w + bias1; h3 = h3 > 0.f ? h3 : 0.f;
                    #pragma unroll
                    for (int c = 0; c < 10; ++c) {
                        lp[0][c] += h0 * wv1[c]; lp[1][c] += h1 * wv1[c];
                        lp[2][c] += h2 * wv1[c]; lp[3][c] += h3 * wv1[c];
                    }
                }
                #pragma unroll
                for (int r2 = 0; r2 < 4; ++r2)
                    #pragma unroll
                    for (int c = 0; c < 10; ++c) {
                        float v = lp[r2][c];
                        v += __shfl_xor(v, 1, 64); v += __shfl_xor(v, 2, 64);
                        v += __shfl_xor(v, 4, 64); v += __shfl_xor(v, 8, 64);
                        lp[r2][c] = v;
                    }
                if (ln == 0) {
                    const int mrow = mt * 16 + quad * 4;
                    #pragma unroll
                    for (int r2 = 0; r2 < 4; ++r2)
                        #pragma unroll
                        for (int c = 0; c < 10; ++c)
                            atomicAdd(&lg[mrow + r2][c], lp[r2][c]);
                }
            }
        }
    }
    __syncthreads();

    // ---- margin check -> exact recompute list ----
    if (t < 64) {
        float l[10];
        #pragma unroll
        for (int c = 0; c < 10; ++c) l[c] = lg[t][c];
        float b0 = -1e30f; int i0 = 0;
        #pragma unroll
        for (int c = 0; c < 10; ++c) if (l[c] > b0) { b0 = l[c]; i0 = c; }
        float b1 = -1e30f; int i1 = 0;
        #pragma unroll
        for (int c = 0; c < 10; ++c) { if (c == i0) continue; if (l[c] > b1) { b1 = l[c]; i1 = c; } }
        float b2v = -1e30f;
        #pragma unroll
        for (int c = 0; c < 10; ++c) { if (c == i0 || c == i1) continue; if (l[c] > b2v) b2v = l[c]; }
        if (b0 - b1 < MARGIN || b1 - b2v < MARGIN) {
            u32 e = atomicAdd(&ecnt, 1u);
            elist[e] = (u32)t;
        }
    }
    __syncthreads();

    // ---- exact fp32 recompute for flagged rows (unrolled x4 for MLP) ----
    {
        const u32 ec = ecnt;
        for (u32 ii = w; ii < ec; ii += 8) {
            const int row = (int)elist[ii];
            const float* xr = x + (size_t)(row0 + row) * 256;
            const int n0_ = lane * 8;
            float ha[8];
            #pragma unroll
            for (int j = 0; j < 8; ++j) ha[j] = 0.f;
            for (int k = 0; k < 256; k += 4) {
                float4 xv4 = *(const float4*)(xr + k);
                float4 wa0 = *(const float4*)(Wt1 + (size_t)(k+0) * 512 + n0_);
                float4 wb0 = *(const float4*)(Wt1 + (size_t)(k+0) * 512 + n0_ + 4);
                float4 wa1 = *(const float4*)(Wt1 + (size_t)(k+1) * 512 + n0_);
                float4 wb1 = *(const float4*)(Wt1 + (size_t)(k+1) * 512 + n0_ + 4);
                float4 wa2 = *(const float4*)(Wt1 + (size_t)(k+2) * 512 + n0_);
                float4 wb2 = *(const float4*)(Wt1 + (size_t)(k+2) * 512 + n0_ + 4);
                float4 wa3 = *(const float4*)(Wt1 + (size_t)(k+3) * 512 + n0_);
                float4 wb3 = *(const float4*)(Wt1 + (size_t)(k+3) * 512 + n0_ + 4);
                ha[0] += xv4.x*wa0.x; ha[1] += xv4.x*wa0.y; ha[2] += xv4.x*wa0.z; ha[3] += xv4.x*wa0.w;
                ha[4] += xv4.x*wb0.x; ha[5] += xv4.x*wb0.y; ha[6] += xv4.x*wb0.z; ha[7] += xv4.x*wb0.w;
                ha[0] += xv4.y*wa1.x; ha[1] += xv4.y*wa1.y; ha[2] += xv4.y*wa1.z; ha[3] += xv4.y*wa1.w;
                ha[4] += xv4.y*wb1.x; ha[5] += xv4.y*wb1.y; ha[6] += xv4.y*wb1.z; ha[7] += xv4.y*wb1.w;
                ha[0] += xv4.z*wa2.x; ha[1] += xv4.z*wa2.y; ha[2] += xv4.z*wa2.z; ha[3] += xv4.z*wa2.w;
                ha[4] += xv4.z*wb2.x; ha[5] += xv4.z*wb2.y; ha[6] += xv4.z*wb2.z; ha[7] += xv4.z*wb2.w;
                ha[0] += xv4.w*wa3.x; ha[1] += xv4.w*wa3.y; ha[2] += xv4.w*wa3.z; ha[3] += xv4.w*wa3.w;
                ha[4] += xv4.w*wb3.x; ha[5] += xv4.w*wb3.y; ha[6] += xv4.w*wb3.z; ha[7] += xv4.w*wb3.w;
            }
            float l10[10];
            #pragma unroll
            for (int c = 0; c < 10; ++c) l10[c] = 0.f;
            #pragma unroll
            for (int j = 0; j < 8; ++j) {
                float h = ha[j] + bt1[n0_ + j]; h = h > 0.f ? h : 0.f;
                #pragma unroll
                for (int c = 0; c < 10; ++c) l10[c] += h * wt2t[c * 512 + n0_ + j];
            }
            #pragma unroll
            for (int c = 0; c < 10; ++c) {
                float v = l10[c];
                v += __shfl_xor(v, 1, 64);  v += __shfl_xor(v, 2, 64);
                v += __shfl_xor(v, 4, 64);  v += __shfl_xor(v, 8, 64);
                v += __shfl_xor(v, 16, 64); v += __shfl_xor(v, 32, 64);
                l10[c] = v;
            }
            if (lane == 0) {
                #pragma unroll
                for (int c = 0; c < 10; ++c) lg[row][c] = l10[c] + bt2[c];
            }
        }
    }
    __syncthreads();

    // ---- bitmap + per-patch row lists ----
    if (t < 64) {
        float l[10];
        #pragma unroll
        for (int c = 0; c < 10; ++c) l[c] = lg[t][c];
        float b0 = -1e30f; int i0 = 0;
        #pragma unroll
        for (int c = 0; c < 10; ++c) if (l[c] > b0) { b0 = l[c]; i0 = c; }
        float b1 = -1e30f; int i1 = 0;
        #pragma unroll
        for (int c = 0; c < 10; ++c) { if (c == i0) continue; if (l[c] > b1) { b1 = l[c]; i1 = c; } }
        u32 exact = 0, fb = 0;
        #pragma unroll
        for (int p = 0; p < 10; ++p) {
            int a = rdds[2 * p], b = rdds[2 * p + 1];
            if (i0 == a && i1 == b) exact |= 1u << p;
            if (i0 == a)            fb    |= 1u << p;
        }
        u32 bits = exact ? exact : fb;
        while (bits) {
            int p = __ffs(bits) - 1;
            bits &= bits - 1;
            u32 idx = atomicAdd(&pcnt[p], 1u);
            plist[p][idx] = (u32)t;
        }
    }
    __syncthreads();
    if (t < 10) {
        int L = (int)pcnt[t];
        for (int base = 0; base < L; base += 16) {
            u32 e = atomicAdd(&nwork, 2u);
            wq[e]   = ((u32)t << 8) | (u32)base;             // g=0
            wq[e+1] = ((u32)t << 8) | 0x80u | (u32)base;     // g=1
        }
    }
    __syncthreads();

    // ---- gated patch nets: bf16 MFMA, items = (p, row-tile, n-half) ----
    {
        const u32 nw = nwork;
        for (u32 ii = w; ii < nw; ii += 8) {
            const u32 item = wq[ii];
            const int p = (int)(item >> 8), g = (int)((item >> 7) & 1), mbase = (int)(item & 127);
            const int Lp = (int)pcnt[p];
            const int mi = mbase + ln;
            const int arow = (mi < Lp) ? (int)plist[p][mi] : (int)plist[p][0];
            const u16* xr = &xhi[arow][0];
            const u16* wb0 = wp1hi + (size_t)p * 32768 + (size_t)(g * 64 + ln) * 256;

            f32x4 acc[4];
            #pragma unroll
            for (int i2 = 0; i2 < 4; ++i2) acc[i2] = (f32x4){0.f,0.f,0.f,0.f};

            int ko = quad * 8;
            bf16x8 b0 = *(const bf16x8*)(wb0 + 0 * 4096 + ko);
            bf16x8 b1 = *(const bf16x8*)(wb0 + 1 * 4096 + ko);
            bf16x8 b2 = *(const bf16x8*)(wb0 + 2 * 4096 + ko);
            bf16x8 b3 = *(const bf16x8*)(wb0 + 3 * 4096 + ko);
            #pragma unroll
            for (int kk = 0; kk < 8; ++kk) {
                bf16x8 n0, n1, n2, n3;
                if (kk < 7) {
                    n0 = *(const bf16x8*)(wb0 + 0 * 4096 + ko + 32);
                    n1 = *(const bf16x8*)(wb0 + 1 * 4096 + ko + 32);
                    n2 = *(const bf16x8*)(wb0 + 2 * 4096 + ko + 32);
                    n3 = *(const bf16x8*)(wb0 + 3 * 4096 + ko + 32);
                }
                bf16x8 a = *(const bf16x8*)(xr + ko);
                acc[0] = MFMA16(a, b0, acc[0]);
                acc[1] = MFMA16(a, b1, acc[1]);
                acc[2] = MFMA16(a, b2, acc[2]);
                acc[3] = MFMA16(a, b3, acc[3]);
                ko += 32;
                b0 = n0; b1 = n1; b2 = n2; b3 = n3;
            }

            float pl[4][10];
            #pragma unroll
            for (int r2 = 0; r2 < 4; ++r2)
                #pragma unroll
                for (int c = 0; c < 10; ++c) pl[r2][c] = 0.f;
            #pragma unroll
            for (int i2 = 0; i2 < 4; ++i2) {
                const int n = g * 64 + i2 * 16 + ln;
                const float bias = bp1[p * 128 + n];
                float wv[10];
                #pragma unroll
                for (int c = 0; c < 10; ++c) wv[c] = wp2t[p * 1280 + c * 128 + n];
                float h0 = acc[i2].x + bias; h0 = h0 > 0.f ? h0 : 0.f;
                float h1 = acc[i2].y + bias; h1 = h1 > 0.f ? h1 : 0.f;
                float h2 = acc[i2].z + bias; h2 = h2 > 0.f ? h2 : 0.f;
                float h3 = acc[i2].w + bias; h3 = h3 > 0.f ? h3 : 0.f;
                #pragma unroll
                for (int c = 0; c < 10; ++c) {
                    pl[0][c] += h0 * wv[c];
                    pl[1][c] += h1 * wv[c];
                    pl[2][c] += h2 * wv[c];
                    pl[3][c] += h3 * wv[c];
                }
            }
            #pragma unroll
            for (int r2 = 0; r2 < 4; ++r2)
                #pragma unroll
                for (int c = 0; c < 10; ++c) {
                    float v = pl[r2][c];
                    v += __shfl_xor(v, 1, 64); v += __shfl_xor(v, 2, 64);
                    v += __shfl_xor(v, 4, 64); v += __shfl_xor(v, 8, 64);
                    pl[r2][c] = v;
                }
            if (ln == 0) {
                #pragma unroll
                for (int r2 = 0; r2 < 4; ++r2) {
                    const int mi2 = mbase + quad * 4 + r2;
                    if (mi2 < Lp) {
                        const int row = (int)plist[p][mi2];
                        #pragma unroll
                        for (int c = 0; c < 10; ++c) {
                            float add = pl[r2][c] + (g == 0 ? bp2[p * 10 + c] : 0.f);
                            atomicAdd(&oacc[row][c], add);
                        }
                    }
                }
            }
        }
    }
    __syncthreads();

    for (int i = t; i < 640; i += 512)
        out[(size_t)row0 * 10 + i] = ((float*)lg)[i] + ((float*)oacc)[i];
}

extern "C" void kernel_launch(void* const* d_in, const int* in_sizes, int n_in,
                              void* d_out, int out_size, void* d_ws, size_t ws_size,
                              hipStream_t stream) {
    const float* x   = (const float*)d_in[0];
    const float* Wt1 = (const float*)d_in[1];
    const float* bt1 = (const float*)d_in[2];
    const float* Wt2 = (const float*)d_in[3];
    const float* bt2 = (const float*)d_in[4];
    const float* Wp1 = (const float*)d_in[5];
    const float* bp1 = (const float*)d_in[6];
    const float* Wp2 = (const float*)d_in[7];
    const float* bp2 = (const float*)d_in[8];
    const int* rdd = (const int*)d_in[9];
    float* out = (float*)d_out;

    u16* wt1hi = (u16*)d_ws;
    u16* wt1lo = wt1hi + 131072;
    u16* wp1hi = wt1lo + 131072;
    float* wt2t = (float*)(wp1hi + 327680);
    float* wp2t = wt2t + 5120;

    hipLaunchKernelGGL(conv_kernel, dim3(113), dim3(256), 0, stream,
                       Wt1, Wp1, Wt2, Wp2, wt1hi, wt1lo, wp1hi, wt2t, wp2t);
    hipLaunchKernelGGL(netsum_kernel, dim3(1024), dim3(512), 0, stream,
                       x, Wt1, bt1, bt2, bp1, bp2, rdd,
                       wt1hi, wt1lo, wp1hi, wt2t, wp2t, out);
}